// Round 1
// baseline (435.603 us; speedup 1.0000x reference)
//
#include <hip/hip_runtime.h>

// FeatureAggregation fused kernel (fp32, vector FMA).
// B=8, C=64, N=16384, K=16, but only k<3 used (reference quirk).
// Chain per point-column (68 -> 128 -> 64 -> 64), BN folded to scale/bias,
// ReLU fused, final sum over 3 columns fused into layer-3 epilogue.

#define BN_EPS 1e-5f

__global__ __launch_bounds__(256) void fa_fused(
    const float* __restrict__ src, const float* __restrict__ tgt,
    const float* __restrict__ feat,
    const float* __restrict__ W1, const float* __restrict__ g1, const float* __restrict__ b1,
    const float* __restrict__ m1, const float* __restrict__ v1,
    const float* __restrict__ W2, const float* __restrict__ g2, const float* __restrict__ b2,
    const float* __restrict__ m2, const float* __restrict__ v2,
    const float* __restrict__ W3, const float* __restrict__ g3, const float* __restrict__ b3,
    const float* __restrict__ m3, const float* __restrict__ v3,
    float* __restrict__ out)
{
    constexpr int N = 16384;
    // X0: [48 cols][68 ch]  (layer-1 input; reused as X2 [48][64] padded to 68)
    // X1: [48 cols][132]    (layer-1 output, stride padded 128->132 for banks)
    __shared__ float X0[48 * 68];
    __shared__ float X1[48 * 132];

    const int t  = threadIdx.x;
    const int b  = blockIdx.x >> 10;          // 8 batches * 1024 tiles
    const int n0 = (blockIdx.x & 1023) << 4;  // 16 points per tile

    // ---------------- build X0 ----------------
    {
        const int p  = t & 15;   // point
        const int cs = t >> 4;   // channel sub-group 0..15
        #pragma unroll
        for (int cb = 0; cb < 4; ++cb) {
            const int c = cb * 16 + cs;
            const float4 f = *reinterpret_cast<const float4*>(
                feat + (((b * 64 + c) * N + n0 + p) * 16));
            X0[(3 * p + 0) * 68 + c] = f.x;
            X0[(3 * p + 1) * 68 + c] = f.y;
            X0[(3 * p + 2) * 68 + c] = f.z;
        }
    }
    if (t < 48) {
        const int p = t / 3, k = t - 3 * p;
        const int nn = n0 + p;
        float d0, d1, d2;
        d0 = src[((b * 3 + 0) * N + nn) * 16 + k] - tgt[(b * 3 + 0) * N + nn];
        d1 = src[((b * 3 + 1) * N + nn) * 16 + k] - tgt[(b * 3 + 1) * N + nn];
        d2 = src[((b * 3 + 2) * N + nn) * 16 + k] - tgt[(b * 3 + 2) * N + nn];
        const float dist = d0 * d0 + d1 * d1 + d2 * d2;
        float* row = &X0[(3 * p + k) * 68];
        row[64] = d0; row[65] = d1; row[66] = d2; row[67] = dist;
    }
    __syncthreads();

    const int p  = t & 15;
    const int og = t >> 4;

    // ---------------- layer 1 : 68 -> 128 ----------------
    {
        const int o0 = og * 8;
        float acc[8][3];
        #pragma unroll
        for (int i = 0; i < 8; ++i) acc[i][0] = acc[i][1] = acc[i][2] = 0.f;
        const float* xr0 = &X0[(3 * p + 0) * 68];
        const float* xr1 = &X0[(3 * p + 1) * 68];
        const float* xr2 = &X0[(3 * p + 2) * 68];
        #pragma unroll 4
        for (int c0 = 0; c0 < 68; c0 += 4) {
            const float4 a0 = *reinterpret_cast<const float4*>(xr0 + c0);
            const float4 a1 = *reinterpret_cast<const float4*>(xr1 + c0);
            const float4 a2 = *reinterpret_cast<const float4*>(xr2 + c0);
            #pragma unroll
            for (int ot = 0; ot < 8; ++ot) {
                const float4 w = *reinterpret_cast<const float4*>(W1 + (o0 + ot) * 68 + c0);
                acc[ot][0] = fmaf(w.x, a0.x, fmaf(w.y, a0.y, fmaf(w.z, a0.z, fmaf(w.w, a0.w, acc[ot][0]))));
                acc[ot][1] = fmaf(w.x, a1.x, fmaf(w.y, a1.y, fmaf(w.z, a1.z, fmaf(w.w, a1.w, acc[ot][1]))));
                acc[ot][2] = fmaf(w.x, a2.x, fmaf(w.y, a2.y, fmaf(w.z, a2.z, fmaf(w.w, a2.w, acc[ot][2]))));
            }
        }
        float y[8][3];
        #pragma unroll
        for (int ot = 0; ot < 8; ++ot) {
            const int o = o0 + ot;
            const float sc = g1[o] / sqrtf(v1[o] + BN_EPS);
            const float tb = b1[o] - m1[o] * sc;
            y[ot][0] = fmaxf(fmaf(sc, acc[ot][0], tb), 0.f);
            y[ot][1] = fmaxf(fmaf(sc, acc[ot][1], tb), 0.f);
            y[ot][2] = fmaxf(fmaf(sc, acc[ot][2], tb), 0.f);
        }
        #pragma unroll
        for (int k = 0; k < 3; ++k) {
            float* dst = &X1[(3 * p + k) * 132 + o0];
            *reinterpret_cast<float4*>(dst)     = make_float4(y[0][k], y[1][k], y[2][k], y[3][k]);
            *reinterpret_cast<float4*>(dst + 4) = make_float4(y[4][k], y[5][k], y[6][k], y[7][k]);
        }
    }
    __syncthreads();

    // ---------------- layer 2 : 128 -> 64 ----------------
    {
        const int o0 = og * 4;
        float acc[4][3];
        #pragma unroll
        for (int i = 0; i < 4; ++i) acc[i][0] = acc[i][1] = acc[i][2] = 0.f;
        const float* xr0 = &X1[(3 * p + 0) * 132];
        const float* xr1 = &X1[(3 * p + 1) * 132];
        const float* xr2 = &X1[(3 * p + 2) * 132];
        #pragma unroll 4
        for (int c0 = 0; c0 < 128; c0 += 4) {
            const float4 a0 = *reinterpret_cast<const float4*>(xr0 + c0);
            const float4 a1 = *reinterpret_cast<const float4*>(xr1 + c0);
            const float4 a2 = *reinterpret_cast<const float4*>(xr2 + c0);
            #pragma unroll
            for (int ot = 0; ot < 4; ++ot) {
                const float4 w = *reinterpret_cast<const float4*>(W2 + (o0 + ot) * 128 + c0);
                acc[ot][0] = fmaf(w.x, a0.x, fmaf(w.y, a0.y, fmaf(w.z, a0.z, fmaf(w.w, a0.w, acc[ot][0]))));
                acc[ot][1] = fmaf(w.x, a1.x, fmaf(w.y, a1.y, fmaf(w.z, a1.z, fmaf(w.w, a1.w, acc[ot][1]))));
                acc[ot][2] = fmaf(w.x, a2.x, fmaf(w.y, a2.y, fmaf(w.z, a2.z, fmaf(w.w, a2.w, acc[ot][2]))));
            }
        }
        float y[4][3];
        #pragma unroll
        for (int ot = 0; ot < 4; ++ot) {
            const int o = o0 + ot;
            const float sc = g2[o] / sqrtf(v2[o] + BN_EPS);
            const float tb = b2[o] - m2[o] * sc;
            y[ot][0] = fmaxf(fmaf(sc, acc[ot][0], tb), 0.f);
            y[ot][1] = fmaxf(fmaf(sc, acc[ot][1], tb), 0.f);
            y[ot][2] = fmaxf(fmaf(sc, acc[ot][2], tb), 0.f);
        }
        // X2 overlays X0 (stride 68); X0 is dead after the L1->L2 barrier.
        #pragma unroll
        for (int k = 0; k < 3; ++k) {
            *reinterpret_cast<float4*>(&X0[(3 * p + k) * 68 + o0]) =
                make_float4(y[0][k], y[1][k], y[2][k], y[3][k]);
        }
    }
    __syncthreads();

    // ---------------- layer 3 : 64 -> 64, + sum over k ----------------
    {
        const int o0 = og * 4;
        float acc[4][3];
        #pragma unroll
        for (int i = 0; i < 4; ++i) acc[i][0] = acc[i][1] = acc[i][2] = 0.f;
        const float* xr0 = &X0[(3 * p + 0) * 68];
        const float* xr1 = &X0[(3 * p + 1) * 68];
        const float* xr2 = &X0[(3 * p + 2) * 68];
        #pragma unroll 4
        for (int c0 = 0; c0 < 64; c0 += 4) {
            const float4 a0 = *reinterpret_cast<const float4*>(xr0 + c0);
            const float4 a1 = *reinterpret_cast<const float4*>(xr1 + c0);
            const float4 a2 = *reinterpret_cast<const float4*>(xr2 + c0);
            #pragma unroll
            for (int ot = 0; ot < 4; ++ot) {
                const float4 w = *reinterpret_cast<const float4*>(W3 + (o0 + ot) * 64 + c0);
                acc[ot][0] = fmaf(w.x, a0.x, fmaf(w.y, a0.y, fmaf(w.z, a0.z, fmaf(w.w, a0.w, acc[ot][0]))));
                acc[ot][1] = fmaf(w.x, a1.x, fmaf(w.y, a1.y, fmaf(w.z, a1.z, fmaf(w.w, a1.w, acc[ot][1]))));
                acc[ot][2] = fmaf(w.x, a2.x, fmaf(w.y, a2.y, fmaf(w.z, a2.z, fmaf(w.w, a2.w, acc[ot][2]))));
            }
        }
        #pragma unroll
        for (int ot = 0; ot < 4; ++ot) {
            const int o = o0 + ot;
            const float sc = g3[o] / sqrtf(v3[o] + BN_EPS);
            const float tb = b3[o] - m3[o] * sc;
            const float r = fmaxf(fmaf(sc, acc[ot][0], tb), 0.f)
                          + fmaxf(fmaf(sc, acc[ot][1], tb), 0.f)
                          + fmaxf(fmaf(sc, acc[ot][2], tb), 0.f);
            out[(b * 64 + o) * N + n0 + p] = r;
        }
    }
}

extern "C" void kernel_launch(void* const* d_in, const int* in_sizes, int n_in,
                              void* d_out, int out_size, void* d_ws, size_t ws_size,
                              hipStream_t stream)
{
    const float* src  = (const float*)d_in[0];
    const float* tgt  = (const float*)d_in[1];
    const float* feat = (const float*)d_in[2];
    const float* W1 = (const float*)d_in[3];
    const float* g1 = (const float*)d_in[4];
    const float* b1 = (const float*)d_in[5];
    const float* m1 = (const float*)d_in[6];
    const float* v1 = (const float*)d_in[7];
    const float* W2 = (const float*)d_in[8];
    const float* g2 = (const float*)d_in[9];
    const float* b2 = (const float*)d_in[10];
    const float* m2 = (const float*)d_in[11];
    const float* v2 = (const float*)d_in[12];
    const float* W3 = (const float*)d_in[13];
    const float* g3 = (const float*)d_in[14];
    const float* b3 = (const float*)d_in[15];
    const float* m3 = (const float*)d_in[16];
    const float* v3 = (const float*)d_in[17];
    float* out = (float*)d_out;

    dim3 grid(8 * 1024);   // B * (N/16)
    dim3 block(256);
    hipLaunchKernelGGL(fa_fused, grid, block, 0, stream,
                       src, tgt, feat,
                       W1, g1, b1, m1, v1,
                       W2, g2, b2, m2, v2,
                       W3, g3, b3, m3, v3,
                       out);
}

// Round 2
// 144.107 us; speedup vs baseline: 3.0228x; 3.0228x over previous
//
#include <hip/hip_runtime.h>

// FeatureAggregation via MFMA bf16 (fp32 accumulate).
// B=8, C=64, N=16384, K=16 but only k<3 used (reference quirk).
// Rows of the "GEMM" are (k*32 + p_local) per 32-point tile: the 3 neighbor
// rows of a point live in the SAME lane across 3 row-tiles -> k-sum is a
// register add and output stores are dwordx4 (full 64B lines).
// Weights pre-packed to B-fragment order + BN folded by fa_pack into d_ws.

typedef __attribute__((ext_vector_type(8))) short short8v;
typedef __attribute__((ext_vector_type(4))) float f32x4;

#define BN_EPS 1e-5f

__device__ __forceinline__ unsigned short f2bf(float f) {
    union { float f; unsigned u; } U; U.f = f;
    unsigned r = U.u + 0x7FFFu + ((U.u >> 16) & 1u);   // RNE; inputs finite
    return (unsigned short)(r >> 16);
}

union FragU { uint4 u; short8v s; uint2 h[2]; };

// ---- d_ws layout (bytes) ----
//     0 : W1 frags uint4[1536]  (frag = ct*3+ks, ct 0..7, ks 0..2; zero-pad k>=68)
// 24576 : W2 frags uint4[1024]  (frag = ct*4+ks, ct 0..3, ks 0..3)
// 40960 : W3 frags uint4[512]   (frag = ct*2+ks, ct 0..3, ks 0..1)
// 49152 : s1[128]  49664 : t1[128]
// 50176 : s2[64]   50432 : t2[64]
// 50688 : s3[64]   50944 : t3[64]   (total 51200 B)

__global__ __launch_bounds__(256) void fa_pack(
    const float* __restrict__ W1, const float* __restrict__ g1, const float* __restrict__ b1,
    const float* __restrict__ m1, const float* __restrict__ v1,
    const float* __restrict__ W2, const float* __restrict__ g2, const float* __restrict__ b2,
    const float* __restrict__ m2, const float* __restrict__ v2,
    const float* __restrict__ W3, const float* __restrict__ g3, const float* __restrict__ b3,
    const float* __restrict__ m3, const float* __restrict__ v3,
    char* __restrict__ ws)
{
    const int id = blockIdx.x * 256 + threadIdx.x;
    if (id < 1536) {                       // W1: 96(K,zero-padded) x 128
        const int lane = id & 63, frag = id >> 6;
        const int ct = frag / 3, ks = frag - 3 * ct;
        const int o  = ct * 16 + (lane & 15);
        const int kb = ks * 32 + (lane >> 4) * 8;
        unsigned short h[8];
        #pragma unroll
        for (int j = 0; j < 8; ++j) {
            const int k = kb + j;
            h[j] = (k < 68) ? f2bf(W1[o * 68 + k]) : (unsigned short)0;
        }
        uint4 pk;
        pk.x = h[0] | (h[1] << 16); pk.y = h[2] | (h[3] << 16);
        pk.z = h[4] | (h[5] << 16); pk.w = h[6] | (h[7] << 16);
        ((uint4*)ws)[id] = pk;
    } else if (id < 2560) {                // W2: 128 x 64
        const int i2 = id - 1536;
        const int lane = i2 & 63, frag = i2 >> 6;
        const int o  = (frag >> 2) * 16 + (lane & 15);
        const int kb = (frag & 3) * 32 + (lane >> 4) * 8;
        unsigned short h[8];
        #pragma unroll
        for (int j = 0; j < 8; ++j) h[j] = f2bf(W2[o * 128 + kb + j]);
        uint4 pk;
        pk.x = h[0] | (h[1] << 16); pk.y = h[2] | (h[3] << 16);
        pk.z = h[4] | (h[5] << 16); pk.w = h[6] | (h[7] << 16);
        ((uint4*)(ws + 24576))[i2] = pk;
    } else if (id < 3072) {                // W3: 64 x 64
        const int i3 = id - 2560;
        const int lane = i3 & 63, frag = i3 >> 6;
        const int o  = (frag >> 1) * 16 + (lane & 15);
        const int kb = (frag & 1) * 32 + (lane >> 4) * 8;
        unsigned short h[8];
        #pragma unroll
        for (int j = 0; j < 8; ++j) h[j] = f2bf(W3[o * 64 + kb + j]);
        uint4 pk;
        pk.x = h[0] | (h[1] << 16); pk.y = h[2] | (h[3] << 16);
        pk.z = h[4] | (h[5] << 16); pk.w = h[6] | (h[7] << 16);
        ((uint4*)(ws + 40960))[i3] = pk;
    } else if (id < 3200) {                // BN fold L1
        const int o = id - 3072;
        const float s = g1[o] * rsqrtf(v1[o] + BN_EPS);
        ((float*)(ws + 49152))[o] = s;
        ((float*)(ws + 49664))[o] = b1[o] - m1[o] * s;
    } else if (id < 3264) {                // BN fold L2
        const int o = id - 3200;
        const float s = g2[o] * rsqrtf(v2[o] + BN_EPS);
        ((float*)(ws + 50176))[o] = s;
        ((float*)(ws + 50432))[o] = b2[o] - m2[o] * s;
    } else if (id < 3328) {                // BN fold L3
        const int o = id - 3264;
        const float s = g3[o] * rsqrtf(v3[o] + BN_EPS);
        ((float*)(ws + 50688))[o] = s;
        ((float*)(ws + 50944))[o] = b3[o] - m3[o] * s;
    }
}

__global__ __launch_bounds__(128, 2) void fa_mfma(
    const float* __restrict__ src, const float* __restrict__ tgt,
    const float* __restrict__ feat,
    const char* __restrict__ ws, float* __restrict__ out)
{
    constexpr int N = 16384;
    // X0: 96 rows x 72 bf16 (cols 0..63 feat, 64..66 diff, 67 dist, 68..71 zero)
    //     later overlaid by X2 (96 x 64 in same stride).
    // X1: 96 rows x 136 bf16 (128 cols + pad).
    __shared__ unsigned short X0[96 * 72];    // 13824 B
    __shared__ unsigned short X1[96 * 136];   // 26112 B  -> total 39936 B

    const int t  = threadIdx.x;
    const int b  = blockIdx.x >> 9;             // 8 batches x 512 tiles
    const int n0 = (blockIdx.x & 511) << 5;     // 32 points per tile

    // ---- stage X0 (bf16) ----
    {
        const int p  = t & 31;
        const int cg = t >> 5;                  // 0..3
        #pragma unroll
        for (int it = 0; it < 4; ++it) {
            const int c0 = it * 16 + cg * 4;
            const float* fp = feat + ((size_t)(b * 64 + c0) * N + n0 + p) * 16;
            const float4 f0 = *(const float4*)(fp);
            const float4 f1 = *(const float4*)(fp + (size_t)N * 16);
            const float4 f2 = *(const float4*)(fp + (size_t)N * 32);
            const float4 f3 = *(const float4*)(fp + (size_t)N * 48);
            uint2 u0, u1, u2;
            u0.x = f2bf(f0.x) | (f2bf(f1.x) << 16); u0.y = f2bf(f2.x) | (f2bf(f3.x) << 16);
            u1.x = f2bf(f0.y) | (f2bf(f1.y) << 16); u1.y = f2bf(f2.y) | (f2bf(f3.y) << 16);
            u2.x = f2bf(f0.z) | (f2bf(f1.z) << 16); u2.y = f2bf(f2.z) | (f2bf(f3.z) << 16);
            *(uint2*)&X0[(0 * 32 + p) * 72 + c0] = u0;
            *(uint2*)&X0[(1 * 32 + p) * 72 + c0] = u1;
            *(uint2*)&X0[(2 * 32 + p) * 72 + c0] = u2;
        }
    }
    if (t < 96) {                               // relation channels + pad zero
        const int p = t & 31, k = t >> 5;
        const int n = n0 + p;
        const float d0 = src[((b * 3 + 0) * N + n) * 16 + k] - tgt[(b * 3 + 0) * N + n];
        const float d1 = src[((b * 3 + 1) * N + n) * 16 + k] - tgt[(b * 3 + 1) * N + n];
        const float d2 = src[((b * 3 + 2) * N + n) * 16 + k] - tgt[(b * 3 + 2) * N + n];
        const float ds = d0 * d0 + d1 * d1 + d2 * d2;
        uint2 wr; wr.x = f2bf(d0) | (f2bf(d1) << 16); wr.y = f2bf(d2) | (f2bf(ds) << 16);
        *(uint2*)&X0[(k * 32 + p) * 72 + 64] = wr;
        uint2 z; z.x = 0; z.y = 0;
        *(uint2*)&X0[(k * 32 + p) * 72 + 68] = z;
    }
    __syncthreads();   // only barrier: afterwards each wave touches only its own rows

    const int w = t >> 6, lane = t & 63, lo = lane & 15, hi = lane >> 4;

    const uint4*  w1f = (const uint4*)ws;
    const uint4*  w2f = (const uint4*)(ws + 24576);
    const uint4*  w3f = (const uint4*)(ws + 40960);
    const float*  s1w = (const float*)(ws + 49152);
    const float*  t1w = (const float*)(ws + 49664);
    const float*  s2w = (const float*)(ws + 50176);
    const float*  t2w = (const float*)(ws + 50432);
    const float*  s3w = (const float*)(ws + 50688);
    const float*  t3w = (const float*)(ws + 50944);

    // ---- layer 1 : K=96 (68 real) -> 128 ----
    short8v a1[3][3];
    #pragma unroll
    for (int k = 0; k < 3; ++k) {
        const int row = k * 32 + w * 16 + lo;
        a1[k][0] = *(const short8v*)&X0[row * 72 + hi * 8];
        a1[k][1] = *(const short8v*)&X0[row * 72 + 32 + hi * 8];
        short8v az = {0, 0, 0, 0, 0, 0, 0, 0};
        if (hi == 0) {                 // k=64..71 (68..71 are zeroed pad)
            FragU U; U.s = az;
            U.h[0] = *(const uint2*)&X0[row * 72 + 64];
            az = U.s;
        }
        a1[k][2] = az;
    }
    #pragma unroll 2
    for (int ct = 0; ct < 8; ++ct) {
        FragU B0, B1, B2;
        B0.u = w1f[(ct * 3 + 0) * 64 + lane];
        B1.u = w1f[(ct * 3 + 1) * 64 + lane];
        B2.u = w1f[(ct * 3 + 2) * 64 + lane];
        const float sc = s1w[ct * 16 + lo];
        const float tb = t1w[ct * 16 + lo];
        #pragma unroll
        for (int k = 0; k < 3; ++k) {
            f32x4 acc = {0.f, 0.f, 0.f, 0.f};
            acc = __builtin_amdgcn_mfma_f32_16x16x32_bf16(a1[k][0], B0.s, acc, 0, 0, 0);
            acc = __builtin_amdgcn_mfma_f32_16x16x32_bf16(a1[k][1], B1.s, acc, 0, 0, 0);
            acc = __builtin_amdgcn_mfma_f32_16x16x32_bf16(a1[k][2], B2.s, acc, 0, 0, 0);
            const int rb = k * 32 + w * 16 + 4 * hi;
            #pragma unroll
            for (int j = 0; j < 4; ++j) {
                const float y = fmaxf(fmaf(sc, acc[j], tb), 0.f);
                X1[(rb + j) * 136 + ct * 16 + lo] = f2bf(y);
            }
        }
    }

    // ---- layer 2 : K=128 -> 64 (output overlays X0) ----
    short8v a2[3][4];
    #pragma unroll
    for (int k = 0; k < 3; ++k) {
        const int row = k * 32 + w * 16 + lo;
        #pragma unroll
        for (int ks = 0; ks < 4; ++ks)
            a2[k][ks] = *(const short8v*)&X1[row * 136 + ks * 32 + hi * 8];
    }
    #pragma unroll 2
    for (int ct = 0; ct < 4; ++ct) {
        FragU B0, B1, B2, B3;
        B0.u = w2f[(ct * 4 + 0) * 64 + lane];
        B1.u = w2f[(ct * 4 + 1) * 64 + lane];
        B2.u = w2f[(ct * 4 + 2) * 64 + lane];
        B3.u = w2f[(ct * 4 + 3) * 64 + lane];
        const float sc = s2w[ct * 16 + lo];
        const float tb = t2w[ct * 16 + lo];
        #pragma unroll
        for (int k = 0; k < 3; ++k) {
            f32x4 acc = {0.f, 0.f, 0.f, 0.f};
            acc = __builtin_amdgcn_mfma_f32_16x16x32_bf16(a2[k][0], B0.s, acc, 0, 0, 0);
            acc = __builtin_amdgcn_mfma_f32_16x16x32_bf16(a2[k][1], B1.s, acc, 0, 0, 0);
            acc = __builtin_amdgcn_mfma_f32_16x16x32_bf16(a2[k][2], B2.s, acc, 0, 0, 0);
            acc = __builtin_amdgcn_mfma_f32_16x16x32_bf16(a2[k][3], B3.s, acc, 0, 0, 0);
            const int rb = k * 32 + w * 16 + 4 * hi;
            #pragma unroll
            for (int j = 0; j < 4; ++j) {
                const float y = fmaxf(fmaf(sc, acc[j], tb), 0.f);
                X0[(rb + j) * 72 + ct * 16 + lo] = f2bf(y);
            }
        }
    }

    // ---- layer 3 : K=64 -> 64, BN+ReLU per k then register k-sum ----
    short8v a3[3][2];
    #pragma unroll
    for (int k = 0; k < 3; ++k) {
        const int row = k * 32 + w * 16 + lo;
        a3[k][0] = *(const short8v*)&X0[row * 72 + hi * 8];
        a3[k][1] = *(const short8v*)&X0[row * 72 + 32 + hi * 8];
    }
    #pragma unroll 2
    for (int ct = 0; ct < 4; ++ct) {
        FragU B0, B1;
        B0.u = w3f[(ct * 2 + 0) * 64 + lane];
        B1.u = w3f[(ct * 2 + 1) * 64 + lane];
        const float sc = s3w[ct * 16 + lo];
        const float tb = t3w[ct * 16 + lo];
        f32x4 acc0 = {0.f, 0.f, 0.f, 0.f};
        f32x4 acc1 = {0.f, 0.f, 0.f, 0.f};
        f32x4 acc2 = {0.f, 0.f, 0.f, 0.f};
        acc0 = __builtin_amdgcn_mfma_f32_16x16x32_bf16(a3[0][0], B0.s, acc0, 0, 0, 0);
        acc0 = __builtin_amdgcn_mfma_f32_16x16x32_bf16(a3[0][1], B1.s, acc0, 0, 0, 0);
        acc1 = __builtin_amdgcn_mfma_f32_16x16x32_bf16(a3[1][0], B0.s, acc1, 0, 0, 0);
        acc1 = __builtin_amdgcn_mfma_f32_16x16x32_bf16(a3[1][1], B1.s, acc1, 0, 0, 0);
        acc2 = __builtin_amdgcn_mfma_f32_16x16x32_bf16(a3[2][0], B0.s, acc2, 0, 0, 0);
        acc2 = __builtin_amdgcn_mfma_f32_16x16x32_bf16(a3[2][1], B1.s, acc2, 0, 0, 0);
        float4 r;
        float* rp = &r.x;
        #pragma unroll
        for (int j = 0; j < 4; ++j) {
            rp[j] = fmaxf(fmaf(sc, acc0[j], tb), 0.f)
                  + fmaxf(fmaf(sc, acc1[j], tb), 0.f)
                  + fmaxf(fmaf(sc, acc2[j], tb), 0.f);
        }
        float* op = out + (size_t)(b * 64 + ct * 16 + lo) * N + n0 + w * 16 + 4 * hi;
        *(float4*)op = r;   // 4 lanes per o cover a full 64B line
    }
}

extern "C" void kernel_launch(void* const* d_in, const int* in_sizes, int n_in,
                              void* d_out, int out_size, void* d_ws, size_t ws_size,
                              hipStream_t stream)
{
    const float* src  = (const float*)d_in[0];
    const float* tgt  = (const float*)d_in[1];
    const float* feat = (const float*)d_in[2];
    const float* W1 = (const float*)d_in[3];
    const float* g1 = (const float*)d_in[4];
    const float* b1 = (const float*)d_in[5];
    const float* m1 = (const float*)d_in[6];
    const float* v1 = (const float*)d_in[7];
    const float* W2 = (const float*)d_in[8];
    const float* g2 = (const float*)d_in[9];
    const float* b2 = (const float*)d_in[10];
    const float* m2 = (const float*)d_in[11];
    const float* v2 = (const float*)d_in[12];
    const float* W3 = (const float*)d_in[13];
    const float* g3 = (const float*)d_in[14];
    const float* b3 = (const float*)d_in[15];
    const float* m3 = (const float*)d_in[16];
    const float* v3 = (const float*)d_in[17];
    float* out = (float*)d_out;
    char* ws = (char*)d_ws;

    hipLaunchKernelGGL(fa_pack, dim3(13), dim3(256), 0, stream,
                       W1, g1, b1, m1, v1, W2, g2, b2, m2, v2, W3, g3, b3, m3, v3, ws);
    hipLaunchKernelGGL(fa_mfma, dim3(8 * 512), dim3(128), 0, stream,
                       src, tgt, feat, ws, out);
}

// Round 4
// 136.724 us; speedup vs baseline: 3.1860x; 1.0540x over previous
//
#include <hip/hip_runtime.h>

// FeatureAggregation via MFMA bf16 (fp32 accumulate). R2 structure (verified
// correct) + LDS overlay for 6 blocks/CU occupancy + batched staging loads.
// B=8, C=64, N=16384, K=16 but only k<3 used (reference quirk).
// GEMM rows = k*32 + p_local per 32-point tile; k-sum is a register add.

typedef __attribute__((ext_vector_type(8))) short short8v;
typedef __attribute__((ext_vector_type(4))) float f32x4;

#define BN_EPS 1e-5f

__device__ __forceinline__ unsigned short f2bf(float f) {
    union { float f; unsigned u; } U; U.f = f;
    unsigned r = U.u + 0x7FFFu + ((U.u >> 16) & 1u);   // RNE; inputs finite
    return (unsigned short)(r >> 16);
}

union FragU { uint4 u; short8v s; uint2 h[2]; };

// ---- d_ws layout (bytes) ----
//     0 : W1 frags uint4[1536]  (frag = ct*3+ks, ct 0..7, ks 0..2; zero-pad k>=68)
// 24576 : W2 frags uint4[1024]  (frag = ct*4+ks, ct 0..3, ks 0..3)
// 40960 : W3 frags uint4[512]   (frag = ct*2+ks, ct 0..3, ks 0..1)
// 49152 : s1[128]  49664 : t1[128]
// 50176 : s2[64]   50432 : t2[64]
// 50688 : s3[64]   50944 : t3[64]

__global__ __launch_bounds__(256) void fa_pack(
    const float* __restrict__ W1, const float* __restrict__ g1, const float* __restrict__ b1,
    const float* __restrict__ m1, const float* __restrict__ v1,
    const float* __restrict__ W2, const float* __restrict__ g2, const float* __restrict__ b2,
    const float* __restrict__ m2, const float* __restrict__ v2,
    const float* __restrict__ W3, const float* __restrict__ g3, const float* __restrict__ b3,
    const float* __restrict__ m3, const float* __restrict__ v3,
    char* __restrict__ ws)
{
    const int id = blockIdx.x * 256 + threadIdx.x;
    if (id < 1536) {                       // W1: 96(K,zero-padded) x 128
        const int lane = id & 63, frag = id >> 6;
        const int ct = frag / 3, ks = frag - 3 * ct;
        const int o  = ct * 16 + (lane & 15);
        const int kb = ks * 32 + (lane >> 4) * 8;
        unsigned short h[8];
        #pragma unroll
        for (int j = 0; j < 8; ++j) {
            const int k = kb + j;
            h[j] = (k < 68) ? f2bf(W1[o * 68 + k]) : (unsigned short)0;
        }
        uint4 pk;
        pk.x = h[0] | (h[1] << 16); pk.y = h[2] | (h[3] << 16);
        pk.z = h[4] | (h[5] << 16); pk.w = h[6] | (h[7] << 16);
        ((uint4*)ws)[id] = pk;
    } else if (id < 2560) {                // W2: 128 x 64
        const int i2 = id - 1536;
        const int lane = i2 & 63, frag = i2 >> 6;
        const int o  = (frag >> 2) * 16 + (lane & 15);
        const int kb = (frag & 3) * 32 + (lane >> 4) * 8;
        unsigned short h[8];
        #pragma unroll
        for (int j = 0; j < 8; ++j) h[j] = f2bf(W2[o * 128 + kb + j]);
        uint4 pk;
        pk.x = h[0] | (h[1] << 16); pk.y = h[2] | (h[3] << 16);
        pk.z = h[4] | (h[5] << 16); pk.w = h[6] | (h[7] << 16);
        ((uint4*)(ws + 24576))[i2] = pk;
    } else if (id < 3072) {                // W3: 64 x 64
        const int i3 = id - 2560;
        const int lane = i3 & 63, frag = i3 >> 6;
        const int o  = (frag >> 1) * 16 + (lane & 15);
        const int kb = (frag & 1) * 32 + (lane >> 4) * 8;
        unsigned short h[8];
        #pragma unroll
        for (int j = 0; j < 8; ++j) h[j] = f2bf(W3[o * 64 + kb + j]);
        uint4 pk;
        pk.x = h[0] | (h[1] << 16); pk.y = h[2] | (h[3] << 16);
        pk.z = h[4] | (h[5] << 16); pk.w = h[6] | (h[7] << 16);
        ((uint4*)(ws + 40960))[i3] = pk;
    } else if (id < 3200) {                // BN fold L1
        const int o = id - 3072;
        const float s = g1[o] * rsqrtf(v1[o] + BN_EPS);
        ((float*)(ws + 49152))[o] = s;
        ((float*)(ws + 49664))[o] = b1[o] - m1[o] * s;
    } else if (id < 3264) {                // BN fold L2
        const int o = id - 3200;
        const float s = g2[o] * rsqrtf(v2[o] + BN_EPS);
        ((float*)(ws + 50176))[o] = s;
        ((float*)(ws + 50432))[o] = b2[o] - m2[o] * s;
    } else if (id < 3328) {                // BN fold L3
        const int o = id - 3264;
        const float s = g3[o] * rsqrtf(v3[o] + BN_EPS);
        ((float*)(ws + 50688))[o] = s;
        ((float*)(ws + 50944))[o] = b3[o] - m3[o] * s;
    }
}

__global__ __launch_bounds__(128, 3) void fa_mfma(
    const float* __restrict__ src, const float* __restrict__ tgt,
    const float* __restrict__ feat,
    const char* __restrict__ ws, float* __restrict__ out)
{
    constexpr int N = 16384;
    // ONE shared buffer, three overlaid views (phases separated by barriers):
    //   X0 view: 96 rows x stride 72 (input staging; later layer-2 output X2)
    //   X1 view: 96 rows x stride 136 (layer-1 output)
    __shared__ unsigned short SM[96 * 136];   // 26112 B -> 6 blocks/CU
    #define X0V(r, c) SM[(r) * 72 + (c)]
    #define X1V(r, c) SM[(r) * 136 + (c)]

    const int t  = threadIdx.x;
    const int b  = blockIdx.x >> 9;             // 8 batches x 512 tiles
    const int n0 = (blockIdx.x & 511) << 5;     // 32 points per tile

    // ---- stage X0: issue ALL global loads before any conversion ----
    {
        const int p  = t & 31;
        const int cg = t >> 5;                  // 0..3
        float4 fr[16];
        #pragma unroll
        for (int it = 0; it < 4; ++it) {
            const float* fp = feat + ((size_t)(b * 64 + it * 16 + cg * 4) * N + n0 + p) * 16;
            #pragma unroll
            for (int q = 0; q < 4; ++q)
                fr[it * 4 + q] = *(const float4*)(fp + (size_t)q * N * 16);
        }
        float rs0 = 0, rs1 = 0, rs2 = 0, rt0 = 0, rt1 = 0, rt2 = 0;
        const bool rel = t < 96;
        const int rp = t & 31, rk = t >> 5;
        if (rel) {
            const int n = n0 + rp;
            rs0 = src[((b * 3 + 0) * N + n) * 16 + rk]; rt0 = tgt[(b * 3 + 0) * N + n];
            rs1 = src[((b * 3 + 1) * N + n) * 16 + rk]; rt1 = tgt[(b * 3 + 1) * N + n];
            rs2 = src[((b * 3 + 2) * N + n) * 16 + rk]; rt2 = tgt[(b * 3 + 2) * N + n];
        }
        #pragma unroll
        for (int it = 0; it < 4; ++it) {
            const int c0 = it * 16 + cg * 4;
            const float4 f0 = fr[it * 4 + 0], f1 = fr[it * 4 + 1];
            const float4 f2 = fr[it * 4 + 2], f3 = fr[it * 4 + 3];
            uint2 u0, u1, u2;
            u0.x = f2bf(f0.x) | (f2bf(f1.x) << 16); u0.y = f2bf(f2.x) | (f2bf(f3.x) << 16);
            u1.x = f2bf(f0.y) | (f2bf(f1.y) << 16); u1.y = f2bf(f2.y) | (f2bf(f3.y) << 16);
            u2.x = f2bf(f0.z) | (f2bf(f1.z) << 16); u2.y = f2bf(f2.z) | (f2bf(f3.z) << 16);
            *(uint2*)&X0V(0 * 32 + p, c0) = u0;
            *(uint2*)&X0V(1 * 32 + p, c0) = u1;
            *(uint2*)&X0V(2 * 32 + p, c0) = u2;
        }
        if (rel) {
            const float d0 = rs0 - rt0, d1 = rs1 - rt1, d2 = rs2 - rt2;
            const float ds = d0 * d0 + d1 * d1 + d2 * d2;
            uint2 wr; wr.x = f2bf(d0) | (f2bf(d1) << 16); wr.y = f2bf(d2) | (f2bf(ds) << 16);
            *(uint2*)&X0V(rk * 32 + rp, 64) = wr;
        }
    }
    __syncthreads();   // B1: X0 staged

    const int w = t >> 6, lane = t & 63, lo = lane & 15, hi = lane >> 4;

    const uint4*  w1f = (const uint4*)ws;
    const uint4*  w2f = (const uint4*)(ws + 24576);
    const uint4*  w3f = (const uint4*)(ws + 40960);
    const float*  s1w = (const float*)(ws + 49152);
    const float*  t1w = (const float*)(ws + 49664);
    const float*  s2w = (const float*)(ws + 50176);
    const float*  t2w = (const float*)(ws + 50432);
    const float*  s3w = (const float*)(ws + 50688);
    const float*  t3w = (const float*)(ws + 50944);

    // ---- layer 1 A-fragments: consume ALL of X0 into registers ----
    short8v a1[3][3];
    #pragma unroll
    for (int k = 0; k < 3; ++k) {
        const int row = k * 32 + w * 16 + lo;
        a1[k][0] = *(const short8v*)&X0V(row, hi * 8);
        a1[k][1] = *(const short8v*)&X0V(row, 32 + hi * 8);
        FragU U; U.u.x = 0; U.u.y = 0; U.u.z = 0; U.u.w = 0;
        if (hi == 0) U.h[0] = *(const uint2*)&X0V(row, 64);
        a1[k][2] = U.s;
    }
    __syncthreads();   // B2: X0 dead, X1 region free

    // ---- layer 1 : K=96 (68 real) -> 128, write X1 ----
    #pragma unroll 2
    for (int ct = 0; ct < 8; ++ct) {
        FragU B0, B1, B2;
        B0.u = w1f[(ct * 3 + 0) * 64 + lane];
        B1.u = w1f[(ct * 3 + 1) * 64 + lane];
        B2.u = w1f[(ct * 3 + 2) * 64 + lane];
        const float sc = s1w[ct * 16 + lo];
        const float tb = t1w[ct * 16 + lo];
        #pragma unroll
        for (int k = 0; k < 3; ++k) {
            f32x4 acc = {0.f, 0.f, 0.f, 0.f};
            acc = __builtin_amdgcn_mfma_f32_16x16x32_bf16(a1[k][0], B0.s, acc, 0, 0, 0);
            acc = __builtin_amdgcn_mfma_f32_16x16x32_bf16(a1[k][1], B1.s, acc, 0, 0, 0);
            acc = __builtin_amdgcn_mfma_f32_16x16x32_bf16(a1[k][2], B2.s, acc, 0, 0, 0);
            const int rb = k * 32 + w * 16 + 4 * hi;
            #pragma unroll
            for (int j = 0; j < 4; ++j) {
                const float y = fmaxf(fmaf(sc, acc[j], tb), 0.f);
                X1V(rb + j, ct * 16 + lo) = f2bf(y);
            }
        }
    }

    // ---- layer 2 A-fragments: consume X1 (wave-private rows) ----
    short8v a2[3][4];
    #pragma unroll
    for (int k = 0; k < 3; ++k) {
        const int row = k * 32 + w * 16 + lo;
        #pragma unroll
        for (int ks = 0; ks < 4; ++ks)
            a2[k][ks] = *(const short8v*)&X1V(row, ks * 32 + hi * 8);
    }
    __syncthreads();   // B3: X1 dead (other wave's rows overlap X2 region)

    // ---- layer 2 : K=128 -> 64, write X2 (X0 view) ----
    #pragma unroll 2
    for (int ct = 0; ct < 4; ++ct) {
        FragU B0, B1, B2, B3;
        B0.u = w2f[(ct * 4 + 0) * 64 + lane];
        B1.u = w2f[(ct * 4 + 1) * 64 + lane];
        B2.u = w2f[(ct * 4 + 2) * 64 + lane];
        B3.u = w2f[(ct * 4 + 3) * 64 + lane];
        const float sc = s2w[ct * 16 + lo];
        const float tb = t2w[ct * 16 + lo];
        #pragma unroll
        for (int k = 0; k < 3; ++k) {
            f32x4 acc = {0.f, 0.f, 0.f, 0.f};
            acc = __builtin_amdgcn_mfma_f32_16x16x32_bf16(a2[k][0], B0.s, acc, 0, 0, 0);
            acc = __builtin_amdgcn_mfma_f32_16x16x32_bf16(a2[k][1], B1.s, acc, 0, 0, 0);
            acc = __builtin_amdgcn_mfma_f32_16x16x32_bf16(a2[k][2], B2.s, acc, 0, 0, 0);
            acc = __builtin_amdgcn_mfma_f32_16x16x32_bf16(a2[k][3], B3.s, acc, 0, 0, 0);
            const int rb = k * 32 + w * 16 + 4 * hi;
            #pragma unroll
            for (int j = 0; j < 4; ++j) {
                const float y = fmaxf(fmaf(sc, acc[j], tb), 0.f);
                X0V(rb + j, ct * 16 + lo) = f2bf(y);
            }
        }
    }

    // ---- layer 3 : K=64 -> 64, BN+ReLU per k then register k-sum ----
    short8v a3[3][2];
    #pragma unroll
    for (int k = 0; k < 3; ++k) {
        const int row = k * 32 + w * 16 + lo;
        a3[k][0] = *(const short8v*)&X0V(row, hi * 8);
        a3[k][1] = *(const short8v*)&X0V(row, 32 + hi * 8);
    }
    #pragma unroll 2
    for (int ct = 0; ct < 4; ++ct) {
        FragU B0, B1;
        B0.u = w3f[(ct * 2 + 0) * 64 + lane];
        B1.u = w3f[(ct * 2 + 1) * 64 + lane];
        const float sc = s3w[ct * 16 + lo];
        const float tb = t3w[ct * 16 + lo];
        f32x4 acc0 = {0.f, 0.f, 0.f, 0.f};
        f32x4 acc1 = {0.f, 0.f, 0.f, 0.f};
        f32x4 acc2 = {0.f, 0.f, 0.f, 0.f};
        acc0 = __builtin_amdgcn_mfma_f32_16x16x32_bf16(a3[0][0], B0.s, acc0, 0, 0, 0);
        acc0 = __builtin_amdgcn_mfma_f32_16x16x32_bf16(a3[0][1], B1.s, acc0, 0, 0, 0);
        acc1 = __builtin_amdgcn_mfma_f32_16x16x32_bf16(a3[1][0], B0.s, acc1, 0, 0, 0);
        acc1 = __builtin_amdgcn_mfma_f32_16x16x32_bf16(a3[1][1], B1.s, acc1, 0, 0, 0);
        acc2 = __builtin_amdgcn_mfma_f32_16x16x32_bf16(a3[2][0], B0.s, acc2, 0, 0, 0);
        acc2 = __builtin_amdgcn_mfma_f32_16x16x32_bf16(a3[2][1], B1.s, acc2, 0, 0, 0);
        float4 r;
        float* rp = &r.x;
        #pragma unroll
        for (int j = 0; j < 4; ++j) {
            rp[j] = fmaxf(fmaf(sc, acc0[j], tb), 0.f)
                  + fmaxf(fmaf(sc, acc1[j], tb), 0.f)
                  + fmaxf(fmaf(sc, acc2[j], tb), 0.f);
        }
        float* op = out + (size_t)(b * 64 + ct * 16 + lo) * N + n0 + w * 16 + 4 * hi;
        *(float4*)op = r;   // 4 lanes per o cover a full 64B line
    }
    #undef X0V
    #undef X1V
}

extern "C" void kernel_launch(void* const* d_in, const int* in_sizes, int n_in,
                              void* d_out, int out_size, void* d_ws, size_t ws_size,
                              hipStream_t stream)
{
    const float* src  = (const float*)d_in[0];
    const float* tgt  = (const float*)d_in[1];
    const float* feat = (const float*)d_in[2];
    const float* W1 = (const float*)d_in[3];
    const float* g1 = (const float*)d_in[4];
    const float* b1 = (const float*)d_in[5];
    const float* m1 = (const float*)d_in[6];
    const float* v1 = (const float*)d_in[7];
    const float* W2 = (const float*)d_in[8];
    const float* g2 = (const float*)d_in[9];
    const float* b2 = (const float*)d_in[10];
    const float* m2 = (const float*)d_in[11];
    const float* v2 = (const float*)d_in[12];
    const float* W3 = (const float*)d_in[13];
    const float* g3 = (const float*)d_in[14];
    const float* b3 = (const float*)d_in[15];
    const float* m3 = (const float*)d_in[16];
    const float* v3 = (const float*)d_in[17];
    float* out = (float*)d_out;
    char* ws = (char*)d_ws;

    hipLaunchKernelGGL(fa_pack, dim3(13), dim3(256), 0, stream,
                       W1, g1, b1, m1, v1, W2, g2, b2, m2, v2, W3, g3, b3, m3, v3, ws);
    hipLaunchKernelGGL(fa_mfma, dim3(8 * 512), dim3(128), 0, stream,
                       src, tgt, feat, ws, out);
}